// Round 1
// baseline (23896.494 us; speedup 1.0000x reference)
//
#include <hip/hip_runtime.h>
#include <cfloat>
#include <cstdint>

#define NTOKS 25601
#define NZERO 25600
#define NPADD 25856
#define PADR  255
#define NLM   256
#define LCHK  101
#define NHEAD 8
#define DHEAD 64
#define DMODEL 512

// ---------------- block reduce helpers ----------------
__device__ __forceinline__ float wredS(float v){
#pragma unroll
  for (int o = 32; o > 0; o >>= 1) v += __shfl_xor(v, o);
  return v;
}
__device__ __forceinline__ float wredM(float v){
#pragma unroll
  for (int o = 32; o > 0; o >>= 1) v = fmaxf(v, __shfl_xor(v, o));
  return v;
}
template<int NT>
__device__ __forceinline__ float blockSum(float v, float* s){
  v = wredS(v);
  if ((threadIdx.x & 63) == 0) s[threadIdx.x >> 6] = v;
  __syncthreads();
  if (threadIdx.x == 0){
    float t = s[0];
#pragma unroll
    for (int i = 1; i < NT/64; i++) t += s[i];
    s[0] = t;
  }
  __syncthreads();
  v = s[0];
  __syncthreads();
  return v;
}
template<int NT>
__device__ __forceinline__ float blockMax(float v, float* s){
  v = wredM(v);
  if ((threadIdx.x & 63) == 0) s[threadIdx.x >> 6] = v;
  __syncthreads();
  if (threadIdx.x == 0){
    float t = s[0];
#pragma unroll
    for (int i = 1; i < NT/64; i++) t = fmaxf(t, s[i]);
    s[0] = t;
  }
  __syncthreads();
  v = s[0];
  __syncthreads();
  return v;
}

// ---------------- generic tiled fp32 GEMM: C = A(MxK) @ B(KxN) [+bias][relu][+=C] ----------------
// flags: 1 = relu, 2 = accumulate into C
__global__ __launch_bounds__(256) void k_gemm(const float* __restrict__ A,
                                              const float* __restrict__ B,
                                              const float* __restrict__ bias,
                                              float* __restrict__ C,
                                              int M, int N, int K, int flags){
  __shared__ float As[16][65];
  __shared__ float Bs[16][65];
  int tid = threadIdx.x;
  int tx = tid & 15, ty = tid >> 4;
  int mBase = blockIdx.y * 64, nBase = blockIdx.x * 64;
  float acc[4][4] = {};
  int ka = tid & 15, ma = tid >> 4;       // A-tile loader coords
  int nb = tid & 63, kb = tid >> 6;       // B-tile loader coords
  for (int k0 = 0; k0 < K; k0 += 16){
#pragma unroll
    for (int i = 0; i < 4; i++){
      int m = mBase + ma + 16*i;
      As[ka][ma + 16*i] = (m < M) ? A[(size_t)m * K + k0 + ka] : 0.f;
    }
#pragma unroll
    for (int i = 0; i < 4; i++){
      Bs[kb + 4*i][nb] = B[(size_t)(k0 + kb + 4*i) * N + nBase + nb];
    }
    __syncthreads();
#pragma unroll
    for (int k = 0; k < 16; k++){
      float a[4], bb[4];
#pragma unroll
      for (int i = 0; i < 4; i++) a[i] = As[k][ty*4 + i];
#pragma unroll
      for (int j = 0; j < 4; j++) bb[j] = Bs[k][tx*4 + j];
#pragma unroll
      for (int i = 0; i < 4; i++)
#pragma unroll
        for (int j = 0; j < 4; j++)
          acc[i][j] = fmaf(a[i], bb[j], acc[i][j]);
    }
    __syncthreads();
  }
#pragma unroll
  for (int i = 0; i < 4; i++){
    int m = mBase + ty*4 + i;
    if (m >= M) continue;
#pragma unroll
    for (int j = 0; j < 4; j++){
      int n = nBase + tx*4 + j;
      float v = acc[i][j];
      if (bias) v += bias[n];
      if (flags & 1) v = fmaxf(v, 0.f);
      size_t idx = (size_t)m * N + n;
      if (flags & 2) v += C[idx];
      C[idx] = v;
    }
  }
}

// ---------------- batched small GEMM (8 heads), M=K=256 fixed, strideA=65536 ----------------
__global__ __launch_bounds__(256) void k_gemm_bat(const float* __restrict__ A,
                                                  const float* __restrict__ B,
                                                  float* __restrict__ C,
                                                  int N, int sB, int sC, float alpha){
  __shared__ float As[16][65];
  __shared__ float Bs[16][65];
  int hh = blockIdx.z;
  const float* Ab = A + (size_t)hh * 65536;
  const float* Bb = B + (size_t)hh * sB;
  float*       Cb = C + (size_t)hh * sC;
  int tid = threadIdx.x;
  int tx = tid & 15, ty = tid >> 4;
  int mBase = blockIdx.y * 64, nBase = blockIdx.x * 64;
  float acc[4][4] = {};
  int ka = tid & 15, ma = tid >> 4;
  int nb = tid & 63, kb = tid >> 6;
  for (int k0 = 0; k0 < 256; k0 += 16){
#pragma unroll
    for (int i = 0; i < 4; i++)
      As[ka][ma + 16*i] = Ab[(size_t)(mBase + ma + 16*i) * 256 + k0 + ka];
#pragma unroll
    for (int i = 0; i < 4; i++)
      Bs[kb + 4*i][nb] = Bb[(size_t)(k0 + kb + 4*i) * N + nBase + nb];
    __syncthreads();
#pragma unroll
    for (int k = 0; k < 16; k++){
      float a[4], bb[4];
#pragma unroll
      for (int i = 0; i < 4; i++) a[i] = As[k][ty*4 + i];
#pragma unroll
      for (int j = 0; j < 4; j++) bb[j] = Bs[k][tx*4 + j];
#pragma unroll
      for (int i = 0; i < 4; i++)
#pragma unroll
        for (int j = 0; j < 4; j++)
          acc[i][j] = fmaf(a[i], bb[j], acc[i][j]);
    }
    __syncthreads();
  }
#pragma unroll
  for (int i = 0; i < 4; i++)
#pragma unroll
    for (int j = 0; j < 4; j++)
      Cb[(size_t)(mBase + ty*4 + i) * N + nBase + tx*4 + j] = alpha * acc[i][j];
}

// ---------------- set cls token row ----------------
__global__ void k_setcls(const float* __restrict__ cls, float* __restrict__ X){
  X[threadIdx.x] = cls[threadIdx.x];
}

// ---------------- layernorm + front-pad into XN (NPADD rows) ----------------
__global__ __launch_bounds__(128) void k_ln_pad(const float* __restrict__ X,
                                                const float* __restrict__ g,
                                                const float* __restrict__ b,
                                                float* __restrict__ XN){
  __shared__ float red[4];
  int row = blockIdx.x;
  float* o = XN + (size_t)row * DMODEL;
  int tid = threadIdx.x;
  if (row < PADR){
    for (int i = tid; i < DMODEL; i += 128) o[i] = 0.f;
    return;
  }
  const float* x = X + (size_t)(row - PADR) * DMODEL;
  float v[4]; float s = 0.f;
#pragma unroll
  for (int i = 0; i < 4; i++){ v[i] = x[tid + 128*i]; s += v[i]; }
  float mu = blockSum<128>(s, red) * (1.f/512.f);
  float q = 0.f;
#pragma unroll
  for (int i = 0; i < 4; i++){ float d = v[i] - mu; q += d*d; }
  float var = blockSum<128>(q, red) * (1.f/512.f);
  float inv = 1.f / sqrtf(var + 1e-5f);
#pragma unroll
  for (int i = 0; i < 4; i++){
    int c = tid + 128*i;
    o[c] = (v[i] - mu) * inv * g[c] + b[c];
  }
}

// ---------------- landmark pooling: QL, KL (h, 256, 64) ----------------
__global__ __launch_bounds__(64) void k_landmark(const float* __restrict__ QKV,
                                                 float* __restrict__ QL,
                                                 float* __restrict__ KL){
  int j = blockIdx.x, hh = blockIdx.y, d = threadIdx.x;
  float sq = 0.f, sk = 0.f;
  for (int i = 0; i < LCHK; i++){
    size_t t = (size_t)j * LCHK + i;
    sq += QKV[t*1536 + hh*64 + d];
    sk += QKV[t*1536 + 512 + hh*64 + d];
  }
  int lo = j * LCHK;
  int cnt = min(LCHK, max(0, lo + LCHK - PADR));
  float div = (float)cnt + 1e-8f;
  QL[((size_t)hh*NLM + j)*64 + d] = sq * 0.125f / div;  // 1/sqrt(64) scale on q
  KL[((size_t)hh*NLM + j)*64 + d] = sk / div;
}

// ---------------- sim2 softmax -> A2 (h,256,256) ----------------
__global__ __launch_bounds__(256) void k_sim2(const float* __restrict__ QL,
                                              const float* __restrict__ KL,
                                              float* __restrict__ A2){
  __shared__ float qi[64];
  __shared__ float red[8];
  int i = blockIdx.x, hh = blockIdx.y, tid = threadIdx.x;
  if (tid < 64) qi[tid] = QL[((size_t)hh*NLM + i)*64 + tid];
  __syncthreads();
  float dot = 0.f;
  const float* kl = KL + ((size_t)hh*NLM + tid)*64;
#pragma unroll 16
  for (int d = 0; d < 64; d++) dot = fmaf(qi[d], kl[d], dot);
  float s = (i >= 2 && tid >= 2) ? dot : -FLT_MAX;
  float m = blockMax<256>(s, red);
  float e = expf(s - m);
  float sum = blockSum<256>(e, red);
  A2[(size_t)hh*65536 + (size_t)i*256 + tid] = e / sum;
}

// ---------------- per-head row/col max of sums ----------------
__global__ __launch_bounds__(256) void k_hmax(const float* __restrict__ A2, float* __restrict__ HM){
  __shared__ float red[8];
  int hh = blockIdx.x, tid = threadIdx.x;
  const float* a = A2 + (size_t)hh*65536;
  float rs = 0.f, cs = 0.f;
  for (int j = 0; j < 256; j++){
    rs += fabsf(a[(size_t)tid*256 + j]);
    cs += fabsf(a[(size_t)j*256 + tid]);
  }
  float rm = blockMax<256>(rs, red);
  float cm = blockMax<256>(cs, red);
  if (tid == 0){ HM[hh] = rm; HM[8 + hh] = cm; }
}

// ---------------- z0 = A2^T / scale ----------------
__global__ __launch_bounds__(256) void k_zinit(const float* __restrict__ A2,
                                               const float* __restrict__ HM,
                                               float* __restrict__ Z){
  int i = blockIdx.x, hh = blockIdx.y, j = threadIdx.x;
  float rm = HM[0], cm = HM[8];
#pragma unroll
  for (int t = 1; t < 8; t++){ rm = fmaxf(rm, HM[t]); cm = fmaxf(cm, HM[8 + t]); }
  float inv = 1.f / (rm * cm);
  Z[(size_t)hh*65536 + (size_t)i*256 + j] = A2[(size_t)hh*65536 + (size_t)j*256 + i] * inv;
}

// ---------------- T = alpha*I - X ----------------
__global__ __launch_bounds__(256) void k_aim(const float* __restrict__ Xm, float* __restrict__ T, float alpha){
  int i = blockIdx.x, hh = blockIdx.y, j = threadIdx.x;
  size_t idx = (size_t)hh*65536 + (size_t)i*256 + j;
  T[idx] = (i == j ? alpha : 0.f) - Xm[idx];
}

// ---------------- streaming a3 @ v with fused softmax -> AV (h,256,64) ----------------
__global__ __launch_bounds__(256) void k_av(const float* __restrict__ QKV,
                                            const float* __restrict__ QL,
                                            float* __restrict__ AV){
  __shared__ float qi[64];
  __shared__ float pbuf[256];
  __shared__ float red[8];
  __shared__ float sred[256];
  int i = blockIdx.x, hh = blockIdx.y, tid = threadIdx.x;
  if (tid < 64) qi[tid] = QL[((size_t)hh*NLM + i)*64 + tid];
  __syncthreads();
  bool rv = (i >= 2);
  float lmax = -FLT_MAX;
  for (int t0 = 0; t0 < NPADD; t0 += 256){
    int t = t0 + tid;
    const float* kp = QKV + (size_t)t*1536 + 512 + hh*64;
    float dot = 0.f;
#pragma unroll 16
    for (int d = 0; d < 64; d++) dot = fmaf(qi[d], kp[d], dot);
    float s = (rv && t >= PADR) ? dot : -FLT_MAX;
    lmax = fmaxf(lmax, s);
  }
  float m = blockMax<256>(lmax, red);
  int d = tid & 63, grp = tid >> 6;
  float lsum = 0.f, accd = 0.f;
  for (int t0 = 0; t0 < NPADD; t0 += 256){
    int t = t0 + tid;
    const float* kp = QKV + (size_t)t*1536 + 512 + hh*64;
    float dot = 0.f;
#pragma unroll 16
    for (int d2 = 0; d2 < 64; d2++) dot = fmaf(qi[d2], kp[d2], dot);
    float s = (rv && t >= PADR) ? dot : -FLT_MAX;
    float e = expf(s - m);
    lsum += e;
    pbuf[tid] = e;
    __syncthreads();
    const float* vp = QKV + (size_t)(t0 + grp*64)*1536 + 1024 + hh*64 + d;
    for (int r = 0; r < 64; r++)
      accd = fmaf(pbuf[grp*64 + r], vp[(size_t)r*1536], accd);
    __syncthreads();
  }
  float sum = blockSum<256>(lsum, red);
  sred[tid] = accd;
  __syncthreads();
  if (tid < 64){
    float o = sred[tid] + sred[64 + tid] + sred[128 + tid] + sred[192 + tid];
    AV[((size_t)hh*NLM + i)*64 + tid] = o / sum;
  }
}

// ---------------- fused per-token: softmax(sim1) @ W2 + depthwise conv residual -> OUT ----------------
__global__ __launch_bounds__(256) void k_out(const float* __restrict__ QKV,
                                             const float* __restrict__ KL,
                                             const float* __restrict__ W2,
                                             const float* __restrict__ RW,
                                             float* __restrict__ OUT){
  __shared__ float qrow[64];
  __shared__ float pbuf[256];
  __shared__ float red[8];
  __shared__ float sred[256];
  int tok = blockIdx.x;        // 0..NTOKS-1
  int tt = tok + PADR;         // row in padded space
  int tid = threadIdx.x;
  int d = tid & 63, grp = tid >> 6;
  for (int hh = 0; hh < NHEAD; hh++){
    if (tid < 64) qrow[tid] = QKV[(size_t)tt*1536 + hh*64 + tid] * 0.125f;
    __syncthreads();
    float dot = 0.f;
    const float* kl = KL + ((size_t)hh*NLM + tid)*64;
#pragma unroll 16
    for (int dd = 0; dd < 64; dd++) dot = fmaf(qrow[dd], kl[dd], dot);
    float s = (tid >= 2) ? dot : -FLT_MAX;
    float m = blockMax<256>(s, red);
    float e = expf(s - m);
    float sum = blockSum<256>(e, red);
    pbuf[tid] = e / sum;
    __syncthreads();
    float acc = 0.f;
    const float* w2p = W2 + ((size_t)hh*NLM + grp*64)*64 + d;
    for (int r = 0; r < 64; r++)
      acc = fmaf(pbuf[grp*64 + r], w2p[(size_t)r*64], acc);
    // depthwise conv residual (33 taps split over 4 groups)
    for (int k = grp; k < 33; k += 4){
      int src = tt + k - 16;
      if (src < NPADD)
        acc = fmaf(RW[hh*33 + k], QKV[(size_t)src*1536 + 1024 + hh*64 + d], acc);
    }
    sred[tid] = acc;
    __syncthreads();
    if (tid < 64)
      OUT[(size_t)tok*DMODEL + hh*64 + tid] =
        sred[tid] + sred[64 + tid] + sred[128 + tid] + sred[192 + tid];
    __syncthreads();
  }
}

// ---------------- PPEG depthwise 7x7 + 5x5 (+f +biases) -> DWOUT ----------------
__global__ __launch_bounds__(256) void k_dw(const float* __restrict__ X,
                                            const float* __restrict__ w7, const float* __restrict__ b7,
                                            const float* __restrict__ w5, const float* __restrict__ b5,
                                            float* __restrict__ DWOUT){
  int p = blockIdx.x;
  int y = p / 160, x = p - y*160;
  int tid = threadIdx.x;
  for (int cc = 0; cc < 2; cc++){
    int c = tid + cc*256;
    float f = X[(size_t)(1 + p)*DMODEL + c];
    float a7 = 0.f, a5 = 0.f;
    for (int dy = -3; dy <= 3; dy++){
      int yy = y + dy; if (yy < 0 || yy >= 160) continue;
      for (int dx = -3; dx <= 3; dx++){
        int xx = x + dx; if (xx < 0 || xx >= 160) continue;
        float v = X[(size_t)(1 + yy*160 + xx)*DMODEL + c];
        a7 = fmaf(v, w7[c*49 + (dy+3)*7 + (dx+3)], a7);
        if (dy >= -2 && dy <= 2 && dx >= -2 && dx <= 2)
          a5 = fmaf(v, w5[c*25 + (dy+2)*5 + (dx+2)], a5);
      }
    }
    DWOUT[(size_t)p*DMODEL + c] = f + a7 + b7[c] + a5 + b5[c];
  }
}

// ---------------- im2col chunk for 3x3 conv ----------------
__global__ void k_im2col(const float* __restrict__ X, float* __restrict__ XCL, int p0){
  int pl = blockIdx.x;      // 0..3199
  int tap = blockIdx.y;     // 0..8
  int p = p0 + pl;
  int y = p / 160, x = p - y*160;
  int dy = tap/3 - 1, dx = tap%3 - 1;
  int yy = y + dy, xx = x + dx;
  bool ok = (yy >= 0 && yy < 160 && xx >= 0 && xx < 160);
  const float* src = X + (size_t)(1 + yy*160 + xx)*DMODEL;
  float* dst = XCL + (size_t)pl*4608 + (size_t)tap*512;
  for (int c = threadIdx.x; c < 512; c += 256)
    dst[c] = ok ? src[c] : 0.f;
}

// ---------------- reorder w3 (co,ci,3,3) -> WB (tap*512+ci, co) ----------------
__global__ void k_wb(const float* __restrict__ w3, float* __restrict__ WB){
  int k = blockIdx.x;           // 0..4607
  int ci = k & 511, tap = k >> 9;
  for (int co = threadIdx.x; co < 512; co += 256)
    WB[(size_t)k*512 + co] = w3[((size_t)co*512 + ci)*9 + tap];
}

// ---------------- copy DWOUT back into X rows 1.. ----------------
__global__ void k_copyX(const float* __restrict__ DWOUT, float* __restrict__ X){
  size_t total = (size_t)NZERO * DMODEL;
  for (size_t i = (size_t)blockIdx.x*256 + threadIdx.x; i < total; i += (size_t)gridDim.x*256)
    X[DMODEL + i] = DWOUT[i];
}

// ---------------- final: LN(token0) + fc2 + sigmoid + argmax ----------------
__global__ __launch_bounds__(256) void k_final(const float* __restrict__ X,
                                               const float* __restrict__ g, const float* __restrict__ b,
                                               const float* __restrict__ fc2w, const float* __restrict__ fc2b,
                                               float* __restrict__ out){
  __shared__ float red[8];
  __shared__ float xn[512];
  int tid = threadIdx.x;
  float v0 = X[tid], v1 = X[256 + tid];
  float mu = blockSum<256>(v0 + v1, red) * (1.f/512.f);
  float d0 = v0 - mu, d1 = v1 - mu;
  float var = blockSum<256>(d0*d0 + d1*d1, red) * (1.f/512.f);
  float inv = 1.f / sqrtf(var + 1e-5f);
  xn[tid]       = d0*inv*g[tid]       + b[tid];
  xn[256 + tid] = d1*inv*g[256 + tid] + b[256 + tid];
  __syncthreads();
  float l0p = xn[tid]*fc2w[tid*2]     + xn[256+tid]*fc2w[(256+tid)*2];
  float l1p = xn[tid]*fc2w[tid*2 + 1] + xn[256+tid]*fc2w[(256+tid)*2 + 1];
  float l0 = blockSum<256>(l0p, red);
  float l1 = blockSum<256>(l1p, red);
  if (tid == 0){
    l0 += fc2b[0]; l1 += fc2b[1];
    out[0] = l0; out[1] = l1;
    out[2] = 1.f/(1.f + expf(-l0));
    out[3] = 1.f/(1.f + expf(-l1));
    out[4] = (l1 > l0) ? 1.f : 0.f;   // jnp.argmax tie-break: first max
  }
}

__global__ void k_ones(float* __restrict__ out, int n){
  int i = blockIdx.x*256 + threadIdx.x;
  if (i < n) out[5 + i] = 1.0f;
}

// ================= host orchestration =================
struct AttnW { const float *g, *b, *qkv, *ow, *ob, *rw; };

static void run_attention(const AttnW& L, float* X, float* XN, float* QKV,
                          float* QL, float* KL, float* A2, float* Z, float* Z2,
                          float* XZ, float* U, float* W, float* AV, float* W2,
                          float* HM, hipStream_t stream){
  k_ln_pad<<<NPADD, 128, 0, stream>>>(X, L.g, L.b, XN);
  k_gemm<<<dim3(1536/64, NPADD/64), 256, 0, stream>>>(XN, L.qkv, nullptr, QKV, NPADD, 1536, 512, 0);
  k_landmark<<<dim3(NLM, NHEAD), 64, 0, stream>>>(QKV, QL, KL);
  k_sim2<<<dim3(NLM, NHEAD), 256, 0, stream>>>(QL, KL, A2);
  k_hmax<<<NHEAD, 256, 0, stream>>>(A2, HM);
  k_zinit<<<dim3(NLM, NHEAD), 256, 0, stream>>>(A2, HM, Z);
  float* zc = Z; float* zn = Z2;
  for (int it = 0; it < 6; it++){
    k_gemm_bat<<<dim3(4,4,NHEAD), 256, 0, stream>>>(A2, zc, XZ, 256, 65536, 65536, 1.f);
    k_aim<<<dim3(NLM, NHEAD), 256, 0, stream>>>(XZ, U, 7.f);
    k_gemm_bat<<<dim3(4,4,NHEAD), 256, 0, stream>>>(XZ, U, W, 256, 65536, 65536, 1.f);
    k_aim<<<dim3(NLM, NHEAD), 256, 0, stream>>>(W, U, 15.f);
    k_gemm_bat<<<dim3(4,4,NHEAD), 256, 0, stream>>>(XZ, U, W, 256, 65536, 65536, 1.f);
    k_aim<<<dim3(NLM, NHEAD), 256, 0, stream>>>(W, U, 13.f);
    k_gemm_bat<<<dim3(4,4,NHEAD), 256, 0, stream>>>(zc, U, zn, 256, 65536, 65536, 0.25f);
    float* t = zc; zc = zn; zn = t;
  }
  k_av<<<dim3(NLM, NHEAD), 256, 0, stream>>>(QKV, QL, AV);
  k_gemm_bat<<<dim3(1,4,NHEAD), 256, 0, stream>>>(zc, AV, W2, 64, 16384, 16384, 1.f);
  // OUT aliases XN (XN is dead after the QKV GEMM)
  float* OUT = XN;
  k_out<<<NTOKS, 256, 0, stream>>>(QKV, KL, W2, L.rw, OUT);
  k_gemm<<<dim3(512/64, (NTOKS + 63)/64), 256, 0, stream>>>(OUT, L.ow, L.ob, X, NTOKS, 512, 512, 2);
}

extern "C" void kernel_launch(void* const* d_in, const int* in_sizes, int n_in,
                              void* d_out, int out_size, void* d_ws, size_t ws_size,
                              hipStream_t stream){
  const float** in = (const float**)d_in;
  // detect input ordering (dict order vs reference-signature order)
  bool dictOrder = (in_sizes[4] == 25088);
  int iw7, ib7, iw5, ib5, iw3, ib3, ing, inb, ifc2w, ifc2b, l1b, l2b;
  if (dictOrder){
    iw7=4; ib7=5; iw5=6; ib5=7; iw3=8; ib3=9; ing=10; inb=11; ifc2w=12; ifc2b=13; l1b=14; l2b=20;
  } else {
    l1b=4; iw7=10; ib7=11; iw5=12; ib5=13; iw3=14; ib3=15; l2b=16; ing=22; inb=23; ifc2w=24; ifc2b=25;
  }
  const float* hin  = in[0];
  const float* fc1w = in[1];
  const float* fc1b = in[2];
  const float* cls  = in[3];
  AttnW L1 { in[l1b], in[l1b+1], in[l1b+2], in[l1b+3], in[l1b+4], in[l1b+5] };
  AttnW L2 { in[l2b], in[l2b+1], in[l2b+2], in[l2b+3], in[l2b+4], in[l2b+5] };

  float* ws = (float*)d_ws;
  float* X   = ws;                               // NTOKS x 512
  float* XN  = X  + (size_t)NTOKS*DMODEL;        // NPADD x 512 (also OUT)
  float* QKV = XN + (size_t)NPADD*DMODEL;        // NPADD x 1536 (PPEG aliases inside)
  float* SM  = QKV + (size_t)NPADD*1536;
  float* QL = SM;            // 8*256*64
  float* KL = QL + 131072;
  float* AV = KL + 131072;
  float* W2 = AV + 131072;
  float* A2 = W2 + 131072;   // 8*256*256 each below
  float* Z  = A2 + 524288;
  float* Z2 = Z  + 524288;
  float* XZ = Z2 + 524288;
  float* U  = XZ + 524288;
  float* W  = U  + 524288;
  float* HM = W  + 524288;   // 64 floats
  // PPEG aliases (inside QKV region, dead at that point)
  float* DWOUT = QKV;                          // 25600 x 512
  float* WB    = QKV + (size_t)NZERO*DMODEL;   // 4608 x 512
  float* XCL   = WB  + (size_t)4608*512;       // 3200 x 4608 chunk

  // ---- fc1 + relu into X rows 1.., cls into row 0
  k_gemm<<<dim3(512/64, NZERO/64), 256, 0, stream>>>(hin, fc1w, fc1b, X + DMODEL, NZERO, 512, 1024, 1);
  k_setcls<<<1, 512, 0, stream>>>(cls, X);

  // ---- attention block 1
  run_attention(L1, X, XN, QKV, QL, KL, A2, Z, Z2, XZ, U, W, AV, W2, HM, stream);

  // ---- PPEG
  k_dw<<<NZERO, 256, 0, stream>>>(X, in[iw7], in[ib7], in[iw5], in[ib5], DWOUT);
  k_wb<<<4608, 256, 0, stream>>>(in[iw3], WB);
  for (int ch = 0; ch < 8; ch++){
    int p0 = ch * 3200;
    k_im2col<<<dim3(3200, 9), 256, 0, stream>>>(X, XCL, p0);
    k_gemm<<<dim3(512/64, 3200/64), 256, 0, stream>>>(XCL, WB, in[ib3], DWOUT + (size_t)p0*DMODEL,
                                                      3200, 512, 4608, 2);
  }
  k_copyX<<<2048, 256, 0, stream>>>(DWOUT, X);

  // ---- attention block 2
  run_attention(L2, X, XN, QKV, QL, KL, A2, Z, Z2, XZ, U, W, AV, W2, HM, stream);

  // ---- final LN(token0) + fc2 + outputs
  k_final<<<1, 256, 0, stream>>>(X, in[ing], in[inb], in[ifc2w], in[ifc2b], (float*)d_out);
  k_ones<<<(51200 + 255)/256, 256, 0, stream>>>((float*)d_out, 51200);
}

// Round 2
// 15723.746 us; speedup vs baseline: 1.5198x; 1.5198x over previous
//
#include <hip/hip_runtime.h>
#include <cfloat>
#include <cstdint>

#define NTOKS 25601
#define NZERO 25600
#define NPADD 25856
#define PADR  255
#define NLM   256
#define LCHK  101
#define NHEAD 8
#define DHEAD 64
#define DMODEL 512

// ---------------- block reduce helpers ----------------
__device__ __forceinline__ float wredS(float v){
#pragma unroll
  for (int o = 32; o > 0; o >>= 1) v += __shfl_xor(v, o);
  return v;
}
__device__ __forceinline__ float wredM(float v){
#pragma unroll
  for (int o = 32; o > 0; o >>= 1) v = fmaxf(v, __shfl_xor(v, o));
  return v;
}
template<int NT>
__device__ __forceinline__ float blockSum(float v, float* s){
  v = wredS(v);
  if ((threadIdx.x & 63) == 0) s[threadIdx.x >> 6] = v;
  __syncthreads();
  if (threadIdx.x == 0){
    float t = s[0];
#pragma unroll
    for (int i = 1; i < NT/64; i++) t += s[i];
    s[0] = t;
  }
  __syncthreads();
  v = s[0];
  __syncthreads();
  return v;
}
template<int NT>
__device__ __forceinline__ float blockMax(float v, float* s){
  v = wredM(v);
  if ((threadIdx.x & 63) == 0) s[threadIdx.x >> 6] = v;
  __syncthreads();
  if (threadIdx.x == 0){
    float t = s[0];
#pragma unroll
    for (int i = 1; i < NT/64; i++) t = fmaxf(t, s[i]);
    s[0] = t;
  }
  __syncthreads();
  v = s[0];
  __syncthreads();
  return v;
}

// ---------------- generic tiled fp32 GEMM: C = A(MxK) @ B(KxN) [+bias][relu][+=C] ----------------
__global__ __launch_bounds__(256) void k_gemm(const float* __restrict__ A,
                                              const float* __restrict__ B,
                                              const float* __restrict__ bias,
                                              float* __restrict__ C,
                                              int M, int N, int K, int flags){
  __shared__ float As[16][65];
  __shared__ float Bs[16][65];
  int tid = threadIdx.x;
  int tx = tid & 15, ty = tid >> 4;
  int mBase = blockIdx.y * 64, nBase = blockIdx.x * 64;
  float acc[4][4] = {};
  int ka = tid & 15, ma = tid >> 4;
  int nb = tid & 63, kb = tid >> 6;
  for (int k0 = 0; k0 < K; k0 += 16){
#pragma unroll
    for (int i = 0; i < 4; i++){
      int m = mBase + ma + 16*i;
      As[ka][ma + 16*i] = (m < M) ? A[(size_t)m * K + k0 + ka] : 0.f;
    }
#pragma unroll
    for (int i = 0; i < 4; i++){
      Bs[kb + 4*i][nb] = B[(size_t)(k0 + kb + 4*i) * N + nBase + nb];
    }
    __syncthreads();
#pragma unroll
    for (int k = 0; k < 16; k++){
      float a[4], bb[4];
#pragma unroll
      for (int i = 0; i < 4; i++) a[i] = As[k][ty*4 + i];
#pragma unroll
      for (int j = 0; j < 4; j++) bb[j] = Bs[k][tx*4 + j];
#pragma unroll
      for (int i = 0; i < 4; i++)
#pragma unroll
        for (int j = 0; j < 4; j++)
          acc[i][j] = fmaf(a[i], bb[j], acc[i][j]);
    }
    __syncthreads();
  }
#pragma unroll
  for (int i = 0; i < 4; i++){
    int m = mBase + ty*4 + i;
    if (m >= M) continue;
#pragma unroll
    for (int j = 0; j < 4; j++){
      int n = nBase + tx*4 + j;
      float v = acc[i][j];
      if (bias) v += bias[n];
      if (flags & 1) v = fmaxf(v, 0.f);
      size_t idx = (size_t)m * N + n;
      if (flags & 2) v += C[idx];
      C[idx] = v;
    }
  }
}

// ---------------- batched small GEMM (8 heads), M=K=256 fixed, strideA=65536 ----------------
__global__ __launch_bounds__(256) void k_gemm_bat(const float* __restrict__ A,
                                                  const float* __restrict__ B,
                                                  float* __restrict__ C,
                                                  int N, int sB, int sC, float alpha){
  __shared__ float As[16][65];
  __shared__ float Bs[16][65];
  int hh = blockIdx.z;
  const float* Ab = A + (size_t)hh * 65536;
  const float* Bb = B + (size_t)hh * sB;
  float*       Cb = C + (size_t)hh * sC;
  int tid = threadIdx.x;
  int tx = tid & 15, ty = tid >> 4;
  int mBase = blockIdx.y * 64, nBase = blockIdx.x * 64;
  float acc[4][4] = {};
  int ka = tid & 15, ma = tid >> 4;
  int nb = tid & 63, kb = tid >> 6;
  for (int k0 = 0; k0 < 256; k0 += 16){
#pragma unroll
    for (int i = 0; i < 4; i++)
      As[ka][ma + 16*i] = Ab[(size_t)(mBase + ma + 16*i) * 256 + k0 + ka];
#pragma unroll
    for (int i = 0; i < 4; i++)
      Bs[kb + 4*i][nb] = Bb[(size_t)(k0 + kb + 4*i) * N + nBase + nb];
    __syncthreads();
#pragma unroll
    for (int k = 0; k < 16; k++){
      float a[4], bb[4];
#pragma unroll
      for (int i = 0; i < 4; i++) a[i] = As[k][ty*4 + i];
#pragma unroll
      for (int j = 0; j < 4; j++) bb[j] = Bs[k][tx*4 + j];
#pragma unroll
      for (int i = 0; i < 4; i++)
#pragma unroll
        for (int j = 0; j < 4; j++)
          acc[i][j] = fmaf(a[i], bb[j], acc[i][j]);
    }
    __syncthreads();
  }
#pragma unroll
  for (int i = 0; i < 4; i++)
#pragma unroll
    for (int j = 0; j < 4; j++)
      Cb[(size_t)(mBase + ty*4 + i) * N + nBase + tx*4 + j] = alpha * acc[i][j];
}

// ---------------- set cls token row ----------------
__global__ void k_setcls(const float* __restrict__ cls, float* __restrict__ X){
  X[threadIdx.x] = cls[threadIdx.x];
}

// ---------------- layernorm + front-pad into XN (NPADD rows) ----------------
__global__ __launch_bounds__(128) void k_ln_pad(const float* __restrict__ X,
                                                const float* __restrict__ g,
                                                const float* __restrict__ b,
                                                float* __restrict__ XN){
  __shared__ float red[4];
  int row = blockIdx.x;
  float* o = XN + (size_t)row * DMODEL;
  int tid = threadIdx.x;
  if (row < PADR){
    for (int i = tid; i < DMODEL; i += 128) o[i] = 0.f;
    return;
  }
  const float* x = X + (size_t)(row - PADR) * DMODEL;
  float v[4]; float s = 0.f;
#pragma unroll
  for (int i = 0; i < 4; i++){ v[i] = x[tid + 128*i]; s += v[i]; }
  float mu = blockSum<128>(s, red) * (1.f/512.f);
  float q = 0.f;
#pragma unroll
  for (int i = 0; i < 4; i++){ float d = v[i] - mu; q += d*d; }
  float var = blockSum<128>(q, red) * (1.f/512.f);
  float inv = 1.f / sqrtf(var + 1e-5f);
#pragma unroll
  for (int i = 0; i < 4; i++){
    int c = tid + 128*i;
    o[c] = (v[i] - mu) * inv * g[c] + b[c];
  }
}

// ---------------- landmark pooling: QL, KL (h, 256, 64) ----------------
__global__ __launch_bounds__(64) void k_landmark(const float* __restrict__ QKV,
                                                 float* __restrict__ QL,
                                                 float* __restrict__ KL){
  int j = blockIdx.x, hh = blockIdx.y, d = threadIdx.x;
  float sq = 0.f, sk = 0.f;
  for (int i = 0; i < LCHK; i++){
    size_t t = (size_t)j * LCHK + i;
    sq += QKV[t*1536 + hh*64 + d];
    sk += QKV[t*1536 + 512 + hh*64 + d];
  }
  int lo = j * LCHK;
  int cnt = min(LCHK, max(0, lo + LCHK - PADR));
  float div = (float)cnt + 1e-8f;
  QL[((size_t)hh*NLM + j)*64 + d] = sq * 0.125f / div;
  KL[((size_t)hh*NLM + j)*64 + d] = sk / div;
}

// ---------------- sim2 softmax -> A2 (h,256,256) ----------------
__global__ __launch_bounds__(256) void k_sim2(const float* __restrict__ QL,
                                              const float* __restrict__ KL,
                                              float* __restrict__ A2){
  __shared__ float qi[64];
  __shared__ float red[8];
  int i = blockIdx.x, hh = blockIdx.y, tid = threadIdx.x;
  if (tid < 64) qi[tid] = QL[((size_t)hh*NLM + i)*64 + tid];
  __syncthreads();
  float dot = 0.f;
  const float* kl = KL + ((size_t)hh*NLM + tid)*64;
#pragma unroll 16
  for (int d = 0; d < 64; d++) dot = fmaf(qi[d], kl[d], dot);
  float s = (i >= 2 && tid >= 2) ? dot : -FLT_MAX;
  float m = blockMax<256>(s, red);
  float e = __expf(s - m);
  float sum = blockSum<256>(e, red);
  A2[(size_t)hh*65536 + (size_t)i*256 + tid] = e / sum;
}

// ---------------- per-head row/col max of sums ----------------
__global__ __launch_bounds__(256) void k_hmax(const float* __restrict__ A2, float* __restrict__ HM){
  __shared__ float red[8];
  int hh = blockIdx.x, tid = threadIdx.x;
  const float* a = A2 + (size_t)hh*65536;
  float rs = 0.f, cs = 0.f;
  for (int j = 0; j < 256; j++){
    rs += fabsf(a[(size_t)tid*256 + j]);
    cs += fabsf(a[(size_t)j*256 + tid]);
  }
  float rm = blockMax<256>(rs, red);
  float cm = blockMax<256>(cs, red);
  if (tid == 0){ HM[hh] = rm; HM[8 + hh] = cm; }
}

// ---------------- z0 = A2^T / scale ----------------
__global__ __launch_bounds__(256) void k_zinit(const float* __restrict__ A2,
                                               const float* __restrict__ HM,
                                               float* __restrict__ Z){
  int i = blockIdx.x, hh = blockIdx.y, j = threadIdx.x;
  float rm = HM[0], cm = HM[8];
#pragma unroll
  for (int t = 1; t < 8; t++){ rm = fmaxf(rm, HM[t]); cm = fmaxf(cm, HM[8 + t]); }
  float inv = 1.f / (rm * cm);
  Z[(size_t)hh*65536 + (size_t)i*256 + j] = A2[(size_t)hh*65536 + (size_t)j*256 + i] * inv;
}

// ---------------- T = alpha*I - X ----------------
__global__ __launch_bounds__(256) void k_aim(const float* __restrict__ Xm, float* __restrict__ T, float alpha){
  int i = blockIdx.x, hh = blockIdx.y, j = threadIdx.x;
  size_t idx = (size_t)hh*65536 + (size_t)i*256 + j;
  T[idx] = (i == j ? alpha : 0.f) - Xm[idx];
}

// ---------------- k_av2: streaming softmax(sim3) @ V with q-group blocking + split-K ----------------
// grid (8 qgroups, 8 heads, 4 token-splits), 256 threads. 32 landmarks per block.
// No max-subtraction (values LN-bounded); split partials combine exactly.
__global__ __launch_bounds__(256) void k_av2(const float* __restrict__ QKV,
                                             const float* __restrict__ QL,
                                             float* __restrict__ AVP,
                                             float* __restrict__ SUMP){
  __shared__ float Qs[32*64];        // [q][d] flat
  __shared__ float Ks[64][68];
  __shared__ float Vs[64][68];
  __shared__ float PsT[64][36];      // [kt][q'] padded for float4
  int qg = blockIdx.x, h = blockIdx.y, split = blockIdx.z;
  int i0 = qg * 32;
  int tid = threadIdx.x;
  // stage QL rows (already scaled by 0.125 in k_landmark)
  for (int idx = tid; idx < 32*64; idx += 256)
    Qs[idx] = QL[(size_t)(h*NLM + i0)*64 + idx];
  int kt = tid & 63, qp = tid >> 6;          // phase1: 1 token, 8 queries
  int dg = tid & 31, qgi = tid >> 5;         // phase2: 2 dims, 4 queries
  float sump[8];
#pragma unroll
  for (int j = 0; j < 8; j++) sump[j] = 0.f;
  float acc[4][2] = {};
  int tbase0 = split * 6464;
  for (int c = 0; c < 101; c++){
    int tb = tbase0 + c*64;
    __syncthreads();   // protect prev-iter reads of Ks/Vs/PsT (and Qs first iter)
    for (int idx = tid; idx < 4096; idx += 256){
      int row = idx >> 6, d = idx & 63;
      const float* src = QKV + (size_t)(tb + row)*1536 + h*64 + d;
      Ks[row][d] = src[512];
      Vs[row][d] = src[1024];
    }
    __syncthreads();
    // phase1: dots + exp -> PsT, sump
    {
      float sdot[8];
#pragma unroll
      for (int j = 0; j < 8; j++) sdot[j] = 0.f;
      for (int d4 = 0; d4 < 16; d4++){
        float4 kv = *(const float4*)&Ks[kt][d4*4];
#pragma unroll
        for (int j = 0; j < 8; j++){
          float4 qv = *(const float4*)&Qs[(qp*8 + j)*64 + d4*4];
          sdot[j] = fmaf(kv.x, qv.x, sdot[j]);
          sdot[j] = fmaf(kv.y, qv.y, sdot[j]);
          sdot[j] = fmaf(kv.z, qv.z, sdot[j]);
          sdot[j] = fmaf(kv.w, qv.w, sdot[j]);
        }
      }
      int t = tb + kt;
      float e[8];
#pragma unroll
      for (int j = 0; j < 8; j++){
        int gi = i0 + qp*8 + j;
        e[j] = (gi >= 2) ? ((t >= PADR) ? __expf(sdot[j]) : 0.f) : 1.f;
        sump[j] += e[j];
      }
      *(float4*)&PsT[kt][qp*8]     = make_float4(e[0], e[1], e[2], e[3]);
      *(float4*)&PsT[kt][qp*8 + 4] = make_float4(e[4], e[5], e[6], e[7]);
    }
    __syncthreads();
    // phase2: P^T @ V accumulate
    for (int k = 0; k < 64; k++){
      float4 p = *(const float4*)&PsT[k][qgi*4];
      float2 v = *(const float2*)&Vs[k][dg*2];
      acc[0][0] = fmaf(p.x, v.x, acc[0][0]); acc[0][1] = fmaf(p.x, v.y, acc[0][1]);
      acc[1][0] = fmaf(p.y, v.x, acc[1][0]); acc[1][1] = fmaf(p.y, v.y, acc[1][1]);
      acc[2][0] = fmaf(p.z, v.x, acc[2][0]); acc[2][1] = fmaf(p.z, v.y, acc[2][1]);
      acc[3][0] = fmaf(p.w, v.x, acc[3][0]); acc[3][1] = fmaf(p.w, v.y, acc[3][1]);
    }
  }
  // reduce sump across the 64 kt-lanes of each wave (wave == qp group)
#pragma unroll
  for (int j = 0; j < 8; j++){
    float t = wredS(sump[j]);
    if (kt == 0)
      SUMP[(size_t)(split*8 + h)*256 + i0 + qp*8 + j] = t;
  }
  // write AV partials
#pragma unroll
  for (int jj = 0; jj < 4; jj++){
    size_t q = i0 + qgi*4 + jj;
    float2 w; w.x = acc[jj][0]; w.y = acc[jj][1];
    *(float2*)&AVP[(((size_t)split*8 + h)*256 + q)*64 + dg*2] = w;
  }
}

// combine split partials: AV = sum(AVP)/sum(SUMP)
__global__ void k_avred(const float* __restrict__ AVP, const float* __restrict__ SUMP,
                        float* __restrict__ AV){
  int i = blockIdx.x, h = blockIdx.y, d = threadIdx.x;
  float s = 0.f, a = 0.f;
#pragma unroll
  for (int sp = 0; sp < 4; sp++){
    s += SUMP[(size_t)(sp*8 + h)*256 + i];
    a += AVP[(((size_t)sp*8 + h)*256 + i)*64 + d];
  }
  AV[((size_t)h*NLM + i)*64 + d] = a / s;
}

// ---------------- k_out2: tiled softmax(sim1) @ W2 + depthwise residual ----------------
// grid (401 token-tiles, 8 heads), 256 threads; 64 tokens per block.
__global__ __launch_bounds__(256) void k_out2(const float* __restrict__ QKV,
                                              const float* __restrict__ KL,
                                              const float* __restrict__ W2,
                                              const float* __restrict__ RW,
                                              float* __restrict__ OUT){
  __shared__ float QsT[64][68];   // [d][r]
  __shared__ float Bs[64][68];    // KL^T chunk [d][j], then W2 chunk [j][d]
  __shared__ float Ps[64][68];    // P chunk [r][j], then O [r][d]
  __shared__ float Vs[96][68];    // V rows t0-16 .. t0+79
  __shared__ float rws[33];
  int h = blockIdx.y, tile = blockIdx.x;
  int t0 = PADR + tile*64;
  int tid = threadIdx.x, tx = tid & 15, ty = tid >> 4;
  int lr = tid >> 6, ld = tid & 63;
  if (tid < 33) rws[tid] = RW[h*33 + tid];
#pragma unroll 4
  for (int rr = 0; rr < 16; rr++){
    int r = rr*4 + lr;
    int t = t0 + r;
    QsT[ld][r] = (t < NPADD) ? QKV[(size_t)t*1536 + h*64 + ld] * 0.125f : 0.f;
  }
#pragma unroll 4
  for (int rr = 0; rr < 24; rr++){
    int rv = rr*4 + lr;
    int t = t0 - 16 + rv;
    Vs[rv][ld] = (t < NPADD) ? QKV[(size_t)t*1536 + 1024 + h*64 + ld] : 0.f;
  }
  float e[4][4][4];   // [chunk][i][jj]
  for (int c = 0; c < 4; c++){
    __syncthreads();
    for (int rr = 0; rr < 16; rr++){
      int j = rr*4 + lr;
      Bs[ld][j] = KL[(size_t)h*16384 + (size_t)(c*64 + j)*64 + ld];
    }
    __syncthreads();
    float sacc[4][4] = {};
    for (int d = 0; d < 64; d++){
      float4 a = *(const float4*)&QsT[d][ty*4];
      float4 b = *(const float4*)&Bs[d][tx*4];
      float av[4] = {a.x, a.y, a.z, a.w};
      float bv[4] = {b.x, b.y, b.z, b.w};
#pragma unroll
      for (int i = 0; i < 4; i++)
#pragma unroll
        for (int j = 0; j < 4; j++)
          sacc[i][j] = fmaf(av[i], bv[j], sacc[i][j]);
    }
#pragma unroll
    for (int i = 0; i < 4; i++)
#pragma unroll
      for (int j = 0; j < 4; j++){
        int jg = c*64 + tx*4 + j;
        e[c][i][j] = (jg >= 2) ? __expf(sacc[i][j]) : 0.f;
      }
  }
  // row sums via 16-lane shuffle
  float inv[4];
#pragma unroll
  for (int i = 0; i < 4; i++){
    float s = 0.f;
#pragma unroll
    for (int c = 0; c < 4; c++)
#pragma unroll
      for (int j = 0; j < 4; j++) s += e[c][i][j];
    for (int o = 1; o < 16; o <<= 1) s += __shfl_xor(s, o);
    inv[i] = 1.f / s;
  }
  // PV: O = P @ W2
  float o_[4][4] = {};
  for (int c = 0; c < 4; c++){
    __syncthreads();
#pragma unroll
    for (int i = 0; i < 4; i++){
      float4 pv;
      pv.x = e[c][i][0]*inv[i]; pv.y = e[c][i][1]*inv[i];
      pv.z = e[c][i][2]*inv[i]; pv.w = e[c][i][3]*inv[i];
      *(float4*)&Ps[ty*4 + i][tx*4] = pv;
    }
    for (int rr = 0; rr < 16; rr++){
      int j = rr*4 + lr;
      Bs[j][ld] = W2[(size_t)h*16384 + (size_t)(c*64 + j)*64 + ld];
    }
    __syncthreads();
    for (int j = 0; j < 64; j++){
      float4 b = *(const float4*)&Bs[j][tx*4];
      float bv[4] = {b.x, b.y, b.z, b.w};
      float av[4];
#pragma unroll
      for (int i = 0; i < 4; i++) av[i] = Ps[ty*4 + i][j];
#pragma unroll
      for (int i = 0; i < 4; i++)
#pragma unroll
        for (int jj = 0; jj < 4; jj++)
          o_[i][jj] = fmaf(av[i], bv[jj], o_[i][jj]);
    }
  }
  __syncthreads();
#pragma unroll
  for (int i = 0; i < 4; i++){
    float4 ov; ov.x = o_[i][0]; ov.y = o_[i][1]; ov.z = o_[i][2]; ov.w = o_[i][3];
    *(float4*)&Ps[ty*4 + i][tx*4] = ov;
  }
  __syncthreads();
  // conv residual + write out
  for (int rgi = 0; rgi < 16; rgi++){
    int r = rgi*4 + lr;
    float a = Ps[r][ld];
#pragma unroll 11
    for (int k = 0; k < 33; k++)
      a = fmaf(rws[k], Vs[r + k][ld], a);
    int tok = tile*64 + r;
    if (tok < NTOKS)
      OUT[(size_t)tok*DMODEL + h*64 + ld] = a;
  }
}

// ---------------- PPEG depthwise 7x7 + 5x5 (+f +biases) -> DWOUT ----------------
__global__ __launch_bounds__(256) void k_dw(const float* __restrict__ X,
                                            const float* __restrict__ w7, const float* __restrict__ b7,
                                            const float* __restrict__ w5, const float* __restrict__ b5,
                                            float* __restrict__ DWOUT){
  int p = blockIdx.x;
  int y = p / 160, x = p - y*160;
  int tid = threadIdx.x;
  for (int cc = 0; cc < 2; cc++){
    int c = tid + cc*256;
    float f = X[(size_t)(1 + p)*DMODEL + c];
    float a7 = 0.f, a5 = 0.f;
    for (int dy = -3; dy <= 3; dy++){
      int yy = y + dy; if (yy < 0 || yy >= 160) continue;
      for (int dx = -3; dx <= 3; dx++){
        int xx = x + dx; if (xx < 0 || xx >= 160) continue;
        float v = X[(size_t)(1 + yy*160 + xx)*DMODEL + c];
        a7 = fmaf(v, w7[c*49 + (dy+3)*7 + (dx+3)], a7);
        if (dy >= -2 && dy <= 2 && dx >= -2 && dx <= 2)
          a5 = fmaf(v, w5[c*25 + (dy+2)*5 + (dx+2)], a5);
      }
    }
    DWOUT[(size_t)p*DMODEL + c] = f + a7 + b7[c] + a5 + b5[c];
  }
}

// ---------------- im2col chunk for 3x3 conv ----------------
__global__ void k_im2col(const float* __restrict__ X, float* __restrict__ XCL, int p0){
  int pl = blockIdx.x;
  int tap = blockIdx.y;
  int p = p0 + pl;
  int y = p / 160, x = p - y*160;
  int dy = tap/3 - 1, dx = tap%3 - 1;
  int yy = y + dy, xx = x + dx;
  bool ok = (yy >= 0 && yy < 160 && xx >= 0 && xx < 160);
  const float* src = X + (size_t)(1 + yy*160 + xx)*DMODEL;
  float* dst = XCL + (size_t)pl*4608 + (size_t)tap*512;
  for (int c = threadIdx.x; c < 512; c += 256)
    dst[c] = ok ? src[c] : 0.f;
}

// ---------------- reorder w3 (co,ci,3,3) -> WB (tap*512+ci, co) ----------------
__global__ void k_wb(const float* __restrict__ w3, float* __restrict__ WB){
  int k = blockIdx.x;
  int ci = k & 511, tap = k >> 9;
  for (int co = threadIdx.x; co < 512; co += 256)
    WB[(size_t)k*512 + co] = w3[((size_t)co*512 + ci)*9 + tap];
}

// ---------------- copy DWOUT back into X rows 1.. ----------------
__global__ void k_copyX(const float* __restrict__ DWOUT, float* __restrict__ X){
  size_t total = (size_t)NZERO * DMODEL;
  for (size_t i = (size_t)blockIdx.x*256 + threadIdx.x; i < total; i += (size_t)gridDim.x*256)
    X[DMODEL + i] = DWOUT[i];
}

// ---------------- final: LN(token0) + fc2 + sigmoid + argmax ----------------
__global__ __launch_bounds__(256) void k_final(const float* __restrict__ X,
                                               const float* __restrict__ g, const float* __restrict__ b,
                                               const float* __restrict__ fc2w, const float* __restrict__ fc2b,
                                               float* __restrict__ out){
  __shared__ float red[8];
  __shared__ float xn[512];
  int tid = threadIdx.x;
  float v0 = X[tid], v1 = X[256 + tid];
  float mu = blockSum<256>(v0 + v1, red) * (1.f/512.f);
  float d0 = v0 - mu, d1 = v1 - mu;
  float var = blockSum<256>(d0*d0 + d1*d1, red) * (1.f/512.f);
  float inv = 1.f / sqrtf(var + 1e-5f);
  xn[tid]       = d0*inv*g[tid]       + b[tid];
  xn[256 + tid] = d1*inv*g[256 + tid] + b[256 + tid];
  __syncthreads();
  float l0p = xn[tid]*fc2w[tid*2]     + xn[256+tid]*fc2w[(256+tid)*2];
  float l1p = xn[tid]*fc2w[tid*2 + 1] + xn[256+tid]*fc2w[(256+tid)*2 + 1];
  float l0 = blockSum<256>(l0p, red);
  float l1 = blockSum<256>(l1p, red);
  if (tid == 0){
    l0 += fc2b[0]; l1 += fc2b[1];
    out[0] = l0; out[1] = l1;
    out[2] = 1.f/(1.f + expf(-l0));
    out[3] = 1.f/(1.f + expf(-l1));
    out[4] = (l1 > l0) ? 1.f : 0.f;
  }
}

__global__ void k_ones(float* __restrict__ out, int n){
  int i = blockIdx.x*256 + threadIdx.x;
  if (i < n) out[5 + i] = 1.0f;
}

// ================= host orchestration =================
struct AttnW { const float *g, *b, *qkv, *ow, *ob, *rw; };

static void run_attention(const AttnW& L, float* X, float* XN, float* QKV,
                          float* QL, float* KL, float* A2, float* Z, float* Z2,
                          float* XZ, float* U, float* W, float* AV, float* W2,
                          float* HM, float* AVP, float* SUMP, hipStream_t stream){
  k_ln_pad<<<NPADD, 128, 0, stream>>>(X, L.g, L.b, XN);
  k_gemm<<<dim3(1536/64, NPADD/64), 256, 0, stream>>>(XN, L.qkv, nullptr, QKV, NPADD, 1536, 512, 0);
  k_landmark<<<dim3(NLM, NHEAD), 64, 0, stream>>>(QKV, QL, KL);
  k_sim2<<<dim3(NLM, NHEAD), 256, 0, stream>>>(QL, KL, A2);
  k_hmax<<<NHEAD, 256, 0, stream>>>(A2, HM);
  k_zinit<<<dim3(NLM, NHEAD), 256, 0, stream>>>(A2, HM, Z);
  float* zc = Z; float* zn = Z2;
  for (int it = 0; it < 6; it++){
    k_gemm_bat<<<dim3(4,4,NHEAD), 256, 0, stream>>>(A2, zc, XZ, 256, 65536, 65536, 1.f);
    k_aim<<<dim3(NLM, NHEAD), 256, 0, stream>>>(XZ, U, 7.f);
    k_gemm_bat<<<dim3(4,4,NHEAD), 256, 0, stream>>>(XZ, U, W, 256, 65536, 65536, 1.f);
    k_aim<<<dim3(NLM, NHEAD), 256, 0, stream>>>(W, U, 15.f);
    k_gemm_bat<<<dim3(4,4,NHEAD), 256, 0, stream>>>(XZ, U, W, 256, 65536, 65536, 1.f);
    k_aim<<<dim3(NLM, NHEAD), 256, 0, stream>>>(W, U, 13.f);
    k_gemm_bat<<<dim3(4,4,NHEAD), 256, 0, stream>>>(zc, U, zn, 256, 65536, 65536, 0.25f);
    float* t = zc; zc = zn; zn = t;
  }
  k_av2<<<dim3(8, NHEAD, 4), 256, 0, stream>>>(QKV, QL, AVP, SUMP);
  k_avred<<<dim3(NLM, NHEAD), 64, 0, stream>>>(AVP, SUMP, AV);
  k_gemm_bat<<<dim3(1,4,NHEAD), 256, 0, stream>>>(zc, AV, W2, 64, 16384, 16384, 1.f);
  float* OUT = XN;
  k_out2<<<dim3((NTOKS + 63)/64, NHEAD), 256, 0, stream>>>(QKV, KL, W2, L.rw, OUT);
  k_gemm<<<dim3(512/64, (NTOKS + 63)/64), 256, 0, stream>>>(OUT, L.ow, L.ob, X, NTOKS, 512, 512, 2);
}

extern "C" void kernel_launch(void* const* d_in, const int* in_sizes, int n_in,
                              void* d_out, int out_size, void* d_ws, size_t ws_size,
                              hipStream_t stream){
  const float** in = (const float**)d_in;
  bool dictOrder = (in_sizes[4] == 25088);
  int iw7, ib7, iw5, ib5, iw3, ib3, ing, inb, ifc2w, ifc2b, l1b, l2b;
  if (dictOrder){
    iw7=4; ib7=5; iw5=6; ib5=7; iw3=8; ib3=9; ing=10; inb=11; ifc2w=12; ifc2b=13; l1b=14; l2b=20;
  } else {
    l1b=4; iw7=10; ib7=11; iw5=12; ib5=13; iw3=14; ib3=15; l2b=16; ing=22; inb=23; ifc2w=24; ifc2b=25;
  }
  const float* hin  = in[0];
  const float* fc1w = in[1];
  const float* fc1b = in[2];
  const float* cls  = in[3];
  AttnW L1 { in[l1b], in[l1b+1], in[l1b+2], in[l1b+3], in[l1b+4], in[l1b+5] };
  AttnW L2 { in[l2b], in[l2b+1], in[l2b+2], in[l2b+3], in[l2b+4], in[l2b+5] };

  float* ws = (float*)d_ws;
  float* X   = ws;
  float* XN  = X  + (size_t)NTOKS*DMODEL;
  float* QKV = XN + (size_t)NPADD*DMODEL;
  float* SM  = QKV + (size_t)NPADD*1536;
  float* QL = SM;
  float* KL = QL + 131072;
  float* AV = KL + 131072;
  float* W2 = AV + 131072;
  float* A2 = W2 + 131072;
  float* Z  = A2 + 524288;
  float* Z2 = Z  + 524288;
  float* XZ = Z2 + 524288;
  float* U  = XZ + 524288;
  float* W  = U  + 524288;
  float* HM = W  + 524288;
  float* AVP  = HM + 64;          // 4*8*256*64
  float* SUMP = AVP + 524288;     // 4*8*256
  float* DWOUT = QKV;
  float* WB    = QKV + (size_t)NZERO*DMODEL;
  float* XCL   = WB  + (size_t)4608*512;

  k_gemm<<<dim3(512/64, NZERO/64), 256, 0, stream>>>(hin, fc1w, fc1b, X + DMODEL, NZERO, 512, 1024, 1);
  k_setcls<<<1, 512, 0, stream>>>(cls, X);

  run_attention(L1, X, XN, QKV, QL, KL, A2, Z, Z2, XZ, U, W, AV, W2, HM, AVP, SUMP, stream);

  k_dw<<<NZERO, 256, 0, stream>>>(X, in[iw7], in[ib7], in[iw5], in[ib5], DWOUT);
  k_wb<<<4608, 256, 0, stream>>>(in[iw3], WB);
  for (int ch = 0; ch < 8; ch++){
    int p0 = ch * 3200;
    k_im2col<<<dim3(3200, 9), 256, 0, stream>>>(X, XCL, p0);
    k_gemm<<<dim3(512/64, 3200/64), 256, 0, stream>>>(XCL, WB, in[ib3], DWOUT + (size_t)p0*DMODEL,
                                                      3200, 512, 4608, 2);
  }
  k_copyX<<<2048, 256, 0, stream>>>(DWOUT, X);

  run_attention(L2, X, XN, QKV, QL, KL, A2, Z, Z2, XZ, U, W, AV, W2, HM, AVP, SUMP, stream);

  k_final<<<1, 256, 0, stream>>>(X, in[ing], in[inb], in[ifc2w], in[ifc2b], (float*)d_out);
  k_ones<<<(51200 + 255)/256, 256, 0, stream>>>((float*)d_out, 51200);
}

// Round 5
// 6211.905 us; speedup vs baseline: 3.8469x; 2.5312x over previous
//
#include <hip/hip_runtime.h>
#include <cfloat>
#include <cstdint>

#define NTOKS 25601
#define NZR   25600
#define NPADD 25856
#define PADR  255
#define NLM   256
#define LCHK  101
#define NHEAD 8
#define DHEAD 64
#define DMODEL 512

typedef __attribute__((ext_vector_type(8))) short bf16x8;
typedef __attribute__((ext_vector_type(4))) float f32x4;

__device__ __forceinline__ unsigned short f2bf(float f){
  unsigned u = __float_as_uint(f);
  unsigned r = (u + 0x7FFFu + ((u >> 16) & 1u)) >> 16;
  return (unsigned short)r;
}

// ---------------- block reduce helpers ----------------
__device__ __forceinline__ float wredS(float v){
#pragma unroll
  for (int o = 32; o > 0; o >>= 1) v += __shfl_xor(v, o);
  return v;
}
__device__ __forceinline__ float wredM(float v){
#pragma unroll
  for (int o = 32; o > 0; o >>= 1) v = fmaxf(v, __shfl_xor(v, o));
  return v;
}
template<int NT>
__device__ __forceinline__ float blockSum(float v, float* s){
  v = wredS(v);
  if ((threadIdx.x & 63) == 0) s[threadIdx.x >> 6] = v;
  __syncthreads();
  if (threadIdx.x == 0){
    float t = s[0];
#pragma unroll
    for (int i = 1; i < NT/64; i++) t += s[i];
    s[0] = t;
  }
  __syncthreads();
  v = s[0];
  __syncthreads();
  return v;
}
template<int NT>
__device__ __forceinline__ float blockMax(float v, float* s){
  v = wredM(v);
  if ((threadIdx.x & 63) == 0) s[threadIdx.x >> 6] = v;
  __syncthreads();
  if (threadIdx.x == 0){
    float t = s[0];
#pragma unroll
    for (int i = 1; i < NT/64; i++) t = fmaxf(t, s[i]);
    s[0] = t;
  }
  __syncthreads();
  v = s[0];
  __syncthreads();
  return v;
}

// ---------------- MFMA bf16 GEMM: C = A(MxK,bf16) @ BT(NxK,bf16)^T [+bias][relu][+=C] ----------------
// flags: 1 = relu, 2 = accumulate into C. Tile 128x128, BK=32, 4 waves.
__global__ __launch_bounds__(256) void k_gemm_bf(const unsigned short* __restrict__ A,
                                                 const unsigned short* __restrict__ BT,
                                                 const float* __restrict__ bias,
                                                 float* __restrict__ C,
                                                 int M, int N, int K, int flags){
  __shared__ __align__(16) unsigned short As[128*32];
  __shared__ __align__(16) unsigned short Bs[128*32];
  int tid = threadIdx.x;
  int lane = tid & 63, wid = tid >> 6;
  int wr = wid >> 1, wc = wid & 1;
  int mBase = blockIdx.y * 128, nBase = blockIdx.x * 128;
  f32x4 acc[4][4];
#pragma unroll
  for (int i = 0; i < 4; i++)
#pragma unroll
    for (int j = 0; j < 4; j++) acc[i][j] = (f32x4){0.f, 0.f, 0.f, 0.f};
  int lr = tid >> 2;          // 0..63
  int lk = (tid & 3) * 8;     // k element offset
  for (int k0 = 0; k0 < K; k0 += 32){
#pragma unroll
    for (int p = 0; p < 2; p++){
      int row = lr + p*64;
      *(uint4*)&As[row*32 + lk] = *(const uint4*)(A + (size_t)(mBase + row) * K + k0 + lk);
      *(uint4*)&Bs[row*32 + lk] = *(const uint4*)(BT + (size_t)(nBase + row) * K + k0 + lk);
    }
    __syncthreads();
    bf16x8 af[4], bg[4];
#pragma unroll
    for (int i = 0; i < 4; i++)
      af[i] = *(const bf16x8*)&As[(wr*64 + i*16 + (lane & 15))*32 + (lane >> 4)*8];
#pragma unroll
    for (int j = 0; j < 4; j++)
      bg[j] = *(const bf16x8*)&Bs[(wc*64 + j*16 + (lane & 15))*32 + (lane >> 4)*8];
#pragma unroll
    for (int i = 0; i < 4; i++)
#pragma unroll
      for (int j = 0; j < 4; j++)
        acc[i][j] = __builtin_amdgcn_mfma_f32_16x16x32_bf16(af[i], bg[j], acc[i][j], 0, 0, 0);
    __syncthreads();
  }
  int cn = lane & 15, rg = lane >> 4;
#pragma unroll
  for (int i = 0; i < 4; i++){
    int rowb = mBase + wr*64 + i*16 + rg*4;
#pragma unroll
    for (int j = 0; j < 4; j++){
      int col = nBase + wc*64 + j*16 + cn;
      float bv = bias ? bias[col] : 0.f;
#pragma unroll
      for (int r = 0; r < 4; r++){
        int row = rowb + r;
        if (row < M){
          float v = acc[i][j][r] + bv;
          if (flags & 1) v = fmaxf(v, 0.f);
          size_t idx = (size_t)row * N + col;
          if (flags & 2) v += C[idx];
          C[idx] = v;
        }
      }
    }
  }
}

// ---------------- weight transpose+convert: W[K][N] f32 -> WT[N][K] bf16 (K,N mult of 64) ----------------
__global__ __launch_bounds__(256) void k_wt(const float* __restrict__ W, unsigned short* __restrict__ WT,
                                            int K, int N){
  __shared__ float t[64][65];
  int k0 = blockIdx.x * 64, n0 = blockIdx.y * 64;
  for (int i = threadIdx.x; i < 4096; i += 256){
    int r = i >> 6, c = i & 63;
    t[r][c] = W[(size_t)(k0 + r) * N + n0 + c];
  }
  __syncthreads();
  for (int i = threadIdx.x; i < 4096; i += 256){
    int r = i >> 6, c = i & 63;
    WT[(size_t)(n0 + r) * K + k0 + c] = f2bf(t[c][r]);
  }
}

// ---------------- conv3 weight: w3 (co,ci,3,3) -> WBT bf16 [co][tap*512+ci] ----------------
__global__ __launch_bounds__(256) void k_wbt(const float* __restrict__ w3, unsigned short* __restrict__ WBT){
  __shared__ float row[4608];
  int co = blockIdx.x;
  for (int i = threadIdx.x; i < 4608; i += 256) row[i] = w3[(size_t)co*4608 + i];
  __syncthreads();
  for (int k = threadIdx.x; k < 4608; k += 256){
    int ci = k & 511, tap = k >> 9;
    WBT[(size_t)co*4608 + k] = f2bf(row[ci*9 + tap]);
  }
}

// ---------------- fp32 -> bf16 cast (n4 = n/4 float4 chunks) ----------------
__global__ void k_cvt(const float* __restrict__ src, unsigned short* __restrict__ dst, int n4){
  int i = blockIdx.x * 256 + threadIdx.x;
  if (i < n4){
    float4 v = ((const float4*)src)[i];
    ushort4 o;
    o.x = f2bf(v.x); o.y = f2bf(v.y); o.z = f2bf(v.z); o.w = f2bf(v.w);
    ((ushort4*)dst)[i] = o;
  }
}

// ---------------- batched small GEMM (8 heads), M=K=256, N param ----------------
__global__ __launch_bounds__(256) void k_gemm_bat(const float* __restrict__ A,
                                                  const float* __restrict__ B,
                                                  float* __restrict__ C,
                                                  int N, int sB, int sC, float alpha){
  __shared__ float As[16][65];
  __shared__ float Bs[16][65];
  int hh = blockIdx.z;
  const float* Ab = A + (size_t)hh * 65536;
  const float* Bb = B + (size_t)hh * sB;
  float*       Cb = C + (size_t)hh * sC;
  int tid = threadIdx.x;
  int tx = tid & 15, ty = tid >> 4;
  int mBase = blockIdx.y * 64, nBase = blockIdx.x * 64;
  float acc[4][4] = {};
  int ka = tid & 15, ma = tid >> 4;
  int nb = tid & 63, kb = tid >> 6;
  for (int k0 = 0; k0 < 256; k0 += 16){
#pragma unroll
    for (int i = 0; i < 4; i++)
      As[ka][ma + 16*i] = Ab[(size_t)(mBase + ma + 16*i) * 256 + k0 + ka];
#pragma unroll
    for (int i = 0; i < 4; i++)
      Bs[kb + 4*i][nb] = Bb[(size_t)(k0 + kb + 4*i) * N + nBase + nb];
    __syncthreads();
#pragma unroll
    for (int k = 0; k < 16; k++){
      float a[4], bb[4];
#pragma unroll
      for (int i = 0; i < 4; i++) a[i] = As[k][ty*4 + i];
#pragma unroll
      for (int j = 0; j < 4; j++) bb[j] = Bs[k][tx*4 + j];
#pragma unroll
      for (int i = 0; i < 4; i++)
#pragma unroll
        for (int j = 0; j < 4; j++)
          acc[i][j] = fmaf(a[i], bb[j], acc[i][j]);
    }
    __syncthreads();
  }
#pragma unroll
  for (int i = 0; i < 4; i++)
#pragma unroll
    for (int j = 0; j < 4; j++)
      Cb[(size_t)(mBase + ty*4 + i) * N + nBase + tx*4 + j] = alpha * acc[i][j];
}

// ---------------- pinv fused GEMM: v=alpha*(A@B); C=v (if writeC); C2=beta*I - v ----------------
__global__ __launch_bounds__(256) void k_gemm_bat2(const float* __restrict__ A,
                                                   const float* __restrict__ B,
                                                   float* __restrict__ C,
                                                   float* __restrict__ C2,
                                                   float alpha, float beta, int writeC){
  __shared__ float As[16][65];
  __shared__ float Bs[16][65];
  int hh = blockIdx.z;
  const float* Ab = A + (size_t)hh * 65536;
  const float* Bb = B + (size_t)hh * 65536;
  int tid = threadIdx.x;
  int tx = tid & 15, ty = tid >> 4;
  int mBase = blockIdx.y * 64, nBase = blockIdx.x * 64;
  float acc[4][4] = {};
  int ka = tid & 15, ma = tid >> 4;
  int nb = tid & 63, kb = tid >> 6;
  for (int k0 = 0; k0 < 256; k0 += 16){
#pragma unroll
    for (int i = 0; i < 4; i++)
      As[ka][ma + 16*i] = Ab[(size_t)(mBase + ma + 16*i) * 256 + k0 + ka];
#pragma unroll
    for (int i = 0; i < 4; i++)
      Bs[kb + 4*i][nb] = Bb[(size_t)(k0 + kb + 4*i) * 256 + nBase + nb];
    __syncthreads();
#pragma unroll
    for (int k = 0; k < 16; k++){
      float a[4], bb[4];
#pragma unroll
      for (int i = 0; i < 4; i++) a[i] = As[k][ty*4 + i];
#pragma unroll
      for (int j = 0; j < 4; j++) bb[j] = Bs[k][tx*4 + j];
#pragma unroll
      for (int i = 0; i < 4; i++)
#pragma unroll
        for (int j = 0; j < 4; j++)
          acc[i][j] = fmaf(a[i], bb[j], acc[i][j]);
    }
    __syncthreads();
  }
#pragma unroll
  for (int i = 0; i < 4; i++)
#pragma unroll
    for (int j = 0; j < 4; j++){
      int m = mBase + ty*4 + i, n = nBase + tx*4 + j;
      size_t idx = (size_t)hh*65536 + (size_t)m*256 + n;
      float v = alpha * acc[i][j];
      if (writeC) C[idx] = v;
      if (C2) C2[idx] = ((m == n) ? beta : 0.f) - v;
    }
}

// ---------------- set cls token row ----------------
__global__ void k_setcls(const float* __restrict__ cls, float* __restrict__ X){
  X[threadIdx.x] = cls[threadIdx.x];
}

// ---------------- layernorm + front-pad into XN ----------------
__global__ __launch_bounds__(128) void k_ln_pad(const float* __restrict__ X,
                                                const float* __restrict__ g,
                                                const float* __restrict__ b,
                                                float* __restrict__ XN){
  __shared__ float red[4];
  int row = blockIdx.x;
  float* o = XN + (size_t)row * DMODEL;
  int tid = threadIdx.x;
  if (row < PADR){
    for (int i = tid; i < DMODEL; i += 128) o[i] = 0.f;
    return;
  }
  const float* x = X + (size_t)(row - PADR) * DMODEL;
  float v[4]; float s = 0.f;
#pragma unroll
  for (int i = 0; i < 4; i++){ v[i] = x[tid + 128*i]; s += v[i]; }
  float mu = blockSum<128>(s, red) * (1.f/512.f);
  float q = 0.f;
#pragma unroll
  for (int i = 0; i < 4; i++){ float d = v[i] - mu; q += d*d; }
  float var = blockSum<128>(q, red) * (1.f/512.f);
  float inv = 1.f / sqrtf(var + 1e-5f);
#pragma unroll
  for (int i = 0; i < 4; i++){
    int c = tid + 128*i;
    o[c] = (v[i] - mu) * inv * g[c] + b[c];
  }
}

// ---------------- landmark pooling ----------------
__global__ __launch_bounds__(64) void k_landmark(const float* __restrict__ QKV,
                                                 float* __restrict__ QL,
                                                 float* __restrict__ KL){
  int j = blockIdx.x, hh = blockIdx.y, d = threadIdx.x;
  float sq = 0.f, sk = 0.f;
  for (int i = 0; i < LCHK; i++){
    size_t t = (size_t)j * LCHK + i;
    sq += QKV[t*1536 + hh*64 + d];
    sk += QKV[t*1536 + 512 + hh*64 + d];
  }
  int lo = j * LCHK;
  int cnt = min(LCHK, max(0, lo + LCHK - PADR));
  float div = (float)cnt + 1e-8f;
  QL[((size_t)hh*NLM + j)*64 + d] = sq * 0.125f / div;
  KL[((size_t)hh*NLM + j)*64 + d] = sk / div;
}

// ---------------- sim2 softmax -> A2 ----------------
__global__ __launch_bounds__(256) void k_sim2(const float* __restrict__ QL,
                                              const float* __restrict__ KL,
                                              float* __restrict__ A2){
  __shared__ float qi[64];
  __shared__ float red[8];
  int i = blockIdx.x, hh = blockIdx.y, tid = threadIdx.x;
  if (tid < 64) qi[tid] = QL[((size_t)hh*NLM + i)*64 + tid];
  __syncthreads();
  float dot = 0.f;
  const float* kl = KL + ((size_t)hh*NLM + tid)*64;
#pragma unroll 16
  for (int d = 0; d < 64; d++) dot = fmaf(qi[d], kl[d], dot);
  float s = (i >= 2 && tid >= 2) ? dot : -FLT_MAX;
  float m = blockMax<256>(s, red);
  float e = __expf(s - m);
  float sum = blockSum<256>(e, red);
  A2[(size_t)hh*65536 + (size_t)i*256 + tid] = e / sum;
}

// ---------------- per-head row/col max of abs sums ----------------
__global__ __launch_bounds__(256) void k_hmax(const float* __restrict__ A2, float* __restrict__ HM){
  __shared__ float red[8];
  int hh = blockIdx.x, tid = threadIdx.x;
  const float* a = A2 + (size_t)hh*65536;
  float rs = 0.f, cs = 0.f;
  for (int j = 0; j < 256; j++){
    rs += fabsf(a[(size_t)tid*256 + j]);
    cs += fabsf(a[(size_t)j*256 + tid]);
  }
  float rm = blockMax<256>(rs, red);
  float cm = blockMax<256>(cs, red);
  if (tid == 0){ HM[hh] = rm; HM[8 + hh] = cm; }
}

// ---------------- z0 = A2^T / scale ----------------
__global__ __launch_bounds__(256) void k_zinit(const float* __restrict__ A2,
                                               const float* __restrict__ HM,
                                               float* __restrict__ Z){
  int i = blockIdx.x, hh = blockIdx.y, j = threadIdx.x;
  float rm = HM[0], cm = HM[8];
#pragma unroll
  for (int t = 1; t < 8; t++){ rm = fmaxf(rm, HM[t]); cm = fmaxf(cm, HM[8 + t]); }
  float inv = 1.f / (rm * cm);
  Z[(size_t)hh*65536 + (size_t)i*256 + j] = A2[(size_t)hh*65536 + (size_t)j*256 + i] * inv;
}

// ---------------- k_av2: streaming softmax(sim3) @ V (q-group blocking + split-K) ----------------
__global__ __launch_bounds__(256) void k_av2(const float* __restrict__ QKV,
                                             const float* __restrict__ QL,
                                             float* __restrict__ AVP,
                                             float* __restrict__ SUMP){
  __shared__ float Qs[32*64];
  __shared__ float Ks[64][68];
  __shared__ float Vs[64][68];
  __shared__ float PsT[64][36];
  int qg = blockIdx.x, h = blockIdx.y, split = blockIdx.z;
  int i0 = qg * 32;
  int tid = threadIdx.x;
  for (int idx = tid; idx < 32*64; idx += 256)
    Qs[idx] = QL[(size_t)(h*NLM + i0)*64 + idx];
  int kt = tid & 63, qp = tid >> 6;
  int dg = tid & 31, qgi = tid >> 5;
  float sump[8];
#pragma unroll
  for (int j = 0; j < 8; j++) sump[j] = 0.f;
  float acc[4][2] = {};
  int tbase0 = split * 6464;
  for (int c = 0; c < 101; c++){
    int tb = tbase0 + c*64;
    __syncthreads();
    for (int idx = tid; idx < 4096; idx += 256){
      int row = idx >> 6, d = idx & 63;
      const float* src = QKV + (size_t)(tb + row)*1536 + h*64 + d;
      Ks[row][d] = src[512];
      Vs[row][d] = src[1024];
    }
    __syncthreads();
    {
      float sdot[8];
#pragma unroll
      for (int j = 0; j < 8; j++) sdot[j] = 0.f;
      for (int d4 = 0; d4 < 16; d4++){
        float4 kv = *(const float4*)&Ks[kt][d4*4];
#pragma unroll
        for (int j = 0; j < 8; j++){
          float4 qv = *(const float4*)&Qs[(qp*8 + j)*64 + d4*4];
          sdot[j] = fmaf(kv.x, qv.x, sdot[j]);
          sdot[j] = fmaf(kv.y, qv.y, sdot[j]);
          sdot[j] = fmaf(kv.z, qv.z, sdot[j]);
          sdot[j] = fmaf(kv.w, qv.w, sdot[j]);
        }
      }
      int t = tb + kt;
      float e[8];
#pragma unroll
      for (int j = 0; j < 8; j++){
        int gi = i0 + qp*8 + j;
        e[j] = (gi >= 2) ? ((t >= PADR) ? __expf(sdot[j]) : 0.f) : 1.f;
        sump[j] += e[j];
      }
      *(float4*)&PsT[kt][qp*8]     = make_float4(e[0], e[1], e[2], e[3]);
      *(float4*)&PsT[kt][qp*8 + 4] = make_float4(e[4], e[5], e[6], e[7]);
    }
    __syncthreads();
    for (int k = 0; k < 64; k++){
      float4 p = *(const float4*)&PsT[k][qgi*4];
      float2 v = *(const float2*)&Vs[k][dg*2];
      acc[0][0] = fmaf(p.x, v.x, acc[0][0]); acc[0][1] = fmaf(p.x, v.y, acc[0][1]);
      acc[1][0] = fmaf(p.y, v.x, acc[1][0]); acc[1][1] = fmaf(p.y, v.y, acc[1][1]);
      acc[2][0] = fmaf(p.z, v.x, acc[2][0]); acc[2][1] = fmaf(p.z, v.y, acc[2][1]);
      acc[3][0] = fmaf(p.w, v.x, acc[3][0]); acc[3][1] = fmaf(p.w, v.y, acc[3][1]);
    }
  }
#pragma unroll
  for (int j = 0; j < 8; j++){
    float t = wredS(sump[j]);
    if (kt == 0)
      SUMP[(size_t)(split*8 + h)*256 + i0 + qp*8 + j] = t;
  }
#pragma unroll
  for (int jj = 0; jj < 4; jj++){
    size_t q = i0 + qgi*4 + jj;
    float2 w; w.x = acc[jj][0]; w.y = acc[jj][1];
    *(float2*)&AVP[(((size_t)split*8 + h)*256 + q)*64 + dg*2] = w;
  }
}

__global__ void k_avred(const float* __restrict__ AVP, const float* __restrict__ SUMP,
                        float* __restrict__ AV){
  int i = blockIdx.x, h = blockIdx.y, d = threadIdx.x;
  float s = 0.f, a = 0.f;
#pragma unroll
  for (int sp = 0; sp < 4; sp++){
    s += SUMP[(size_t)(sp*8 + h)*256 + i];
    a += AVP[(((size_t)sp*8 + h)*256 + i)*64 + d];
  }
  AV[((size_t)h*NLM + i)*64 + d] = a / s;
}

// ---------------- k_out2: tiled softmax(sim1) @ W2 + depthwise residual ----------------
__global__ __launch_bounds__(256) void k_out2(const float* __restrict__ QKV,
                                              const float* __restrict__ KL,
                                              const float* __restrict__ W2,
                                              const float* __restrict__ RW,
                                              float* __restrict__ OUT){
  __shared__ float QsT[64][68];
  __shared__ float Bs[64][68];
  __shared__ float Ps[64][68];
  __shared__ float Vs[96][68];
  __shared__ float rws[33];
  int h = blockIdx.y, tile = blockIdx.x;
  int t0 = PADR + tile*64;
  int tid = threadIdx.x, tx = tid & 15, ty = tid >> 4;
  int lr = tid >> 6, ld = tid & 63;
  if (tid < 33) rws[tid] = RW[h*33 + tid];
#pragma unroll 4
  for (int rr = 0; rr < 16; rr++){
    int r = rr*4 + lr;
    int t = t0 + r;
    QsT[ld][r] = (t < NPADD) ? QKV[(size_t)t*1536 + h*64 + ld] * 0.125f : 0.f;
  }
#pragma unroll 4
  for (int rr = 0; rr < 24; rr++){
    int rv = rr*4 + lr;
    int t = t0 - 16 + rv;
    Vs[rv][ld] = (t < NPADD) ? QKV[(size_t)t*1536 + 1024 + h*64 + ld] : 0.f;
  }
  float e[4][4][4];
  for (int c = 0; c < 4; c++){
    __syncthreads();
    for (int rr = 0; rr < 16; rr++){
      int j = rr*4 + lr;
      Bs[ld][j] = KL[(size_t)h*16384 + (size_t)(c*64 + j)*64 + ld];
    }
    __syncthreads();
    float sacc[4][4] = {};
    for (int d = 0; d < 64; d++){
      float4 a = *(const float4*)&QsT[d][ty*4];
      float4 b = *(const float4*)&Bs[d][tx*4];
      float av[4] = {a.x, a.y, a.z, a.w};
      float bv[4] = {b.x, b.y, b.z, b.w};
#pragma unroll
      for (int i = 0; i < 4; i++)
#pragma unroll
        for (int j = 0; j < 4; j++)
          sacc[i][j] = fmaf(av[i], bv[j], sacc[i][j]);
    }
#pragma unroll
    for (int i = 0; i < 4; i++)
#pragma unroll
      for (int j = 0; j < 4; j++){
        int jg = c*64 + tx*4 + j;
        e[c][i][j] = (jg >= 2) ? __expf(sacc[i][j]) : 0.f;
      }
  }
  float inv[4];
#pragma unroll
  for (int i = 0; i < 4; i++){
    float s = 0.f;
#pragma unroll
    for (int c = 0; c < 4; c++)
#pragma unroll
      for (int j = 0; j < 4; j++) s += e[c][i][j];
    for (int o = 1; o < 16; o <<= 1) s += __shfl_xor(s, o);
    inv[i] = 1.f / s;
  }
  float o_[4][4] = {};
  for (int c = 0; c < 4; c++){
    __syncthreads();
#pragma unroll
    for (int i = 0; i < 4; i++){
      float4 pv;
      pv.x = e[c][i][0]*inv[i]; pv.y = e[c][i][1]*inv[i];
      pv.z = e[c][i][2]*inv[i]; pv.w = e[c][i][3]*inv[i];
      *(float4*)&Ps[ty*4 + i][tx*4] = pv;
    }
    for (int rr = 0; rr < 16; rr++){
      int j = rr*4 + lr;
      Bs[j][ld] = W2[(size_t)h*16384 + (size_t)(c*64 + j)*64 + ld];
    }
    __syncthreads();
    for (int j = 0; j < 64; j++){
      float4 b = *(const float4*)&Bs[j][tx*4];
      float bv[4] = {b.x, b.y, b.z, b.w};
      float av[4];
#pragma unroll
      for (int i = 0; i < 4; i++) av[i] = Ps[ty*4 + i][j];
#pragma unroll
      for (int i = 0; i < 4; i++)
#pragma unroll
        for (int jj = 0; jj < 4; jj++)
          o_[i][jj] = fmaf(av[i], bv[jj], o_[i][jj]);
    }
  }
  __syncthreads();
#pragma unroll
  for (int i = 0; i < 4; i++){
    float4 ov; ov.x = o_[i][0]; ov.y = o_[i][1]; ov.z = o_[i][2]; ov.w = o_[i][3];
    *(float4*)&Ps[ty*4 + i][tx*4] = ov;
  }
  __syncthreads();
  for (int rgi = 0; rgi < 16; rgi++){
    int r = rgi*4 + lr;
    float a = Ps[r][ld];
#pragma unroll 11
    for (int k = 0; k < 33; k++)
      a = fmaf(rws[k], Vs[r + k][ld], a);
    int tok = tile*64 + r;
    if (tok < NTOKS)
      OUT[(size_t)tok*DMODEL + h*64 + ld] = a;
  }
}

// ---------------- k_dw2: tiled depthwise 7x7+5x5, 16x16 spatial x 16 ch per block ----------------
__global__ __launch_bounds__(256) void k_dw2(const float* __restrict__ X,
                                             const float* __restrict__ w7, const float* __restrict__ b7,
                                             const float* __restrict__ w5, const float* __restrict__ b5,
                                             float* __restrict__ DWOUT){
  __shared__ float Xs[484][17];    // 22x22 halo x 16ch (+pad)
  __shared__ float ws7[16*49];
  __shared__ float ws5[16*25];
  int bx = blockIdx.x, cg = blockIdx.y;
  int tileY = bx / 10, tileX = bx - tileY*10;
  int ty0 = tileY*16 - 3, tx0 = tileX*16 - 3;
  int tid = threadIdx.x;
  for (int i = tid; i < 484*4; i += 256){
    int r = i >> 2, q = i & 3;
    int py = r / 22, px = r - py*22;
    int gy = ty0 + py, gx = tx0 + px;
    float4 v = make_float4(0.f, 0.f, 0.f, 0.f);
    if (gy >= 0 && gy < 160 && gx >= 0 && gx < 160)
      v = *(const float4*)&X[(size_t)(1 + gy*160 + gx)*DMODEL + cg*16 + q*4];
    *(float4*)&Xs[r][q*4] = v;
  }
  for (int i = tid; i < 16*49; i += 256) ws7[i] = w7[cg*16*49 + i];
  for (int i = tid; i < 16*25; i += 256) ws5[i] = w5[cg*16*25 + i];
  __syncthreads();
  int c = tid & 15, pg = tid >> 4;
  float acc[16];
#pragma unroll
  for (int px = 0; px < 16; px++)
    acc[px] = Xs[(pg+3)*22 + px+3][c];
  for (int dy = 0; dy < 7; dy++)
#pragma unroll
    for (int dx = 0; dx < 7; dx++){
      float w = ws7[c*49 + dy*7 + dx];
      int rb = (pg + dy)*22 + dx;
#pragma unroll
      for (int px = 0; px < 16; px++)
        acc[px] = fmaf(Xs[rb + px][c], w, acc[px]);
    }
  for (int dy = 0; dy < 5; dy++)
#pragma unroll
    for (int dx = 0; dx < 5; dx++){
      float w = ws5[c*25 + dy*5 + dx];
      int rb = (pg + 1 + dy)*22 + 1 + dx;
#pragma unroll
      for (int px = 0; px < 16; px++)
        acc[px] = fmaf(Xs[rb + px][c], w, acc[px]);
    }
  float bb = b7[cg*16 + c] + b5[cg*16 + c];
  int gy = tileY*16 + pg;
#pragma unroll
  for (int px = 0; px < 16; px++){
    int p = gy*160 + tileX*16 + px;
    DWOUT[(size_t)p*DMODEL + cg*16 + c] = acc[px] + bb;
  }
}

// ---------------- im2col -> bf16 ----------------
__global__ void k_im2col_bf(const float* __restrict__ X, unsigned short* __restrict__ XCL, int p0){
  int pl = blockIdx.x;
  int tap = blockIdx.y;
  int p = p0 + pl;
  int y = p / 160, x = p - y*160;
  int dy = tap/3 - 1, dx = tap%3 - 1;
  int yy = y + dy, xx = x + dx;
  bool ok = (yy >= 0 && yy < 160 && xx >= 0 && xx < 160);
  const float2* src = (const float2*)(X + (size_t)(1 + yy*160 + xx)*DMODEL);
  ushort2* dst = (ushort2*)(XCL + (size_t)pl*4608 + tap*512);
  int c = threadIdx.x;
  float2 v = ok ? src[c] : make_float2(0.f, 0.f);
  ushort2 o; o.x = f2bf(v.x); o.y = f2bf(v.y);
  dst[c] = o;
}

// ---------------- copy DWOUT back into X rows 1.. ----------------
__global__ void k_copyX(const float* __restrict__ DWOUT, float* __restrict__ X){
  size_t total = (size_t)NZR * DMODEL;
  for (size_t i = (size_t)blockIdx.x*256 + threadIdx.x; i < total; i += (size_t)gridDim.x*256)
    X[DMODEL + i] = DWOUT[i];
}

// ---------------- final: LN(token0) + fc2 + sigmoid + argmax ----------------
__global__ __launch_bounds__(256) void k_final(const float* __restrict__ X,
                                               const float* __restrict__ g, const float* __restrict__ b,
                                               const float* __restrict__ fc2w, const float* __restrict__ fc2b,
                                               float* __restrict__ out){
  __shared__ float red[8];
  __shared__ float xn[512];
  int tid = threadIdx.x;
  float v0 = X[tid], v1 = X[256 + tid];
  float mu = blockSum<256>(v0 + v1, red) * (1.f/512.f);
  float d0 = v0 - mu, d1 = v1 - mu;
  float var = blockSum<256>(d0*d0 + d1*d1, red) * (1.f/512.f);
  float inv = 1.f / sqrtf(var + 1e-5f);
  xn[tid]       = d0*inv*g[tid]       + b[tid];
  xn[256 + tid] = d1*inv*g[256 + tid] + b[256 + tid];
  __syncthreads();
  float l0p = xn[tid]*fc2w[tid*2]     + xn[256+tid]*fc2w[(256+tid)*2];
  float l1p = xn[tid]*fc2w[tid*2 + 1] + xn[256+tid]*fc2w[(256+tid)*2 + 1];
  float l0 = blockSum<256>(l0p, red);
  float l1 = blockSum<256>(l1p, red);
  if (tid == 0){
    l0 += fc2b[0]; l1 += fc2b[1];
    out[0] = l0; out[1] = l1;
    out[2] = 1.f/(1.f + expf(-l0));
    out[3] = 1.f/(1.f + expf(-l1));
    out[4] = (l1 > l0) ? 1.f : 0.f;
  }
}

__global__ void k_ones(float* __restrict__ out, int n){
  int i = blockIdx.x*256 + threadIdx.x;
  if (i < n) out[5 + i] = 1.0f;
}

// ================= host orchestration =================
struct AttnW { const float *g, *b, *qkv, *ow, *ob, *rw; };

static void run_attention(const AttnW& L, float* X, float* XN, float* QKV,
                          float* QL, float* KL, float* A2, float* Z, float* Z2,
                          float* XZ, float* U, float* W, float* AV, float* W2,
                          float* HM, float* AVP, float* SUMP,
                          unsigned short* ABF, unsigned short* WT, hipStream_t stream){
  k_ln_pad<<<NPADD, 128, 0, stream>>>(X, L.g, L.b, XN);
  k_cvt<<<(NPADD*DMODEL/4 + 255)/256, 256, 0, stream>>>(XN, ABF, NPADD*DMODEL/4);
  k_wt<<<dim3(512/64, 1536/64), 256, 0, stream>>>(L.qkv, WT, 512, 1536);
  k_gemm_bf<<<dim3(1536/128, NPADD/128), 256, 0, stream>>>(ABF, WT, nullptr, QKV, NPADD, 1536, 512, 0);
  k_landmark<<<dim3(NLM, NHEAD), 64, 0, stream>>>(QKV, QL, KL);
  k_sim2<<<dim3(NLM, NHEAD), 256, 0, stream>>>(QL, KL, A2);
  k_hmax<<<NHEAD, 256, 0, stream>>>(A2, HM);
  k_zinit<<<dim3(NLM, NHEAD), 256, 0, stream>>>(A2, HM, Z);
  float* zc = Z; float* zn = Z2;
  for (int it = 0; it < 6; it++){
    k_gemm_bat2<<<dim3(4,4,NHEAD), 256, 0, stream>>>(A2, zc, XZ, U, 1.f, 7.f, 1);
    k_gemm_bat2<<<dim3(4,4,NHEAD), 256, 0, stream>>>(XZ, U, W, W, 1.f, 15.f, 0);
    k_gemm_bat2<<<dim3(4,4,NHEAD), 256, 0, stream>>>(XZ, W, U, U, 1.f, 13.f, 0);
    k_gemm_bat2<<<dim3(4,4,NHEAD), 256, 0, stream>>>(zc, U, zn, nullptr, 0.25f, 0.f, 1);
    float* t = zc; zc = zn; zn = t;
  }
  k_av2<<<dim3(8, NHEAD, 4), 256, 0, stream>>>(QKV, QL, AVP, SUMP);
  k_avred<<<dim3(NLM, NHEAD), 64, 0, stream>>>(AVP, SUMP, AV);
  k_gemm_bat<<<dim3(1,4,NHEAD), 256, 0, stream>>>(zc, AV, W2, 64, 16384, 16384, 1.f);
  float* OUT = XN;
  k_out2<<<dim3((NTOKS + 63)/64, NHEAD), 256, 0, stream>>>(QKV, KL, W2, L.rw, OUT);
  k_cvt<<<(NTOKS*DMODEL/4 + 255)/256, 256, 0, stream>>>(OUT, ABF, NTOKS*DMODEL/4);
  k_wt<<<dim3(512/64, 512/64), 256, 0, stream>>>(L.ow, WT, 512, 512);
  k_gemm_bf<<<dim3(512/128, (NTOKS + 127)/128), 256, 0, stream>>>(ABF, WT, L.ob, X, NTOKS, 512, 512, 2);
}

extern "C" void kernel_launch(void* const* d_in, const int* in_sizes, int n_in,
                              void* d_out, int out_size, void* d_ws, size_t ws_size,
                              hipStream_t stream){
  const float** in = (const float**)d_in;
  bool dictOrder = (in_sizes[4] == 25088);
  int iw7, ib7, iw5, ib5, iw3, ib3, ing, inb, ifc2w, ifc2b, l1b, l2b;
  if (dictOrder){
    iw7=4; ib7=5; iw5=6; ib5=7; iw3=8; ib3=9; ing=10; inb=11; ifc2w=12; ifc2b=13; l1b=14; l2b=20;
  } else {
    l1b=4; iw7=10; ib7=11; iw5=12; ib5=13; iw3=14; ib3=15; l2b=16; ing=22; inb=23; ifc2w=24; ifc2b=25;
  }
  const float* hin  = in[0];
  const float* fc1w = in[1];
  const float* fc1b = in[2];
  const float* cls  = in[3];
  AttnW L1 { in[l1b], in[l1b+1], in[l1b+2], in[l1b+3], in[l1b+4], in[l1b+5] };
  AttnW L2 { in[l2b], in[l2b+1], in[l2b+2], in[l2b+3], in[l2b+4], in[l2b+5] };

  float* ws = (float*)d_ws;
  float* X   = ws;                               // 25601 x 512
  float* XN  = X  + (size_t)NTOKS*DMODEL;        // 25856 x 512 (also OUT)
  float* QKV = XN + (size_t)NPADD*DMODEL;        // 25856 x 1536
  float* SM  = QKV + (size_t)NPADD*1536;
  float* QL = SM;
  float* KL = QL + 131072;
  float* AV = KL + 131072;
  float* W2 = AV + 131072;
  float* A2 = W2 + 131072;
  float* Z  = A2 + 524288;
  float* Z2 = Z  + 524288;
  float* XZ = Z2 + 524288;
  float* U  = XZ + 524288;
  float* W  = U  + 524288;
  float* HM = W  + 524288;       // 64
  float* AVP  = HM + 64;         // 4*8*256*64
  float* SUMP = AVP + 524288;    // 8192
  unsigned short* ABF = (unsigned short*)(SUMP + 8192);       // 25856x512 bf16
  unsigned short* WT  = (unsigned short*)A2;                  // alias A2 (dead when WT in use)
  // PPEG aliases inside QKV region (dead then)
  float* DWOUT = QKV;                                         // 25600 x 512 f32
  unsigned short* WBT = (unsigned short*)(QKV + (size_t)NZR*DMODEL);        // 512x4608 bf16
  unsigned short* XCL = WBT + (size_t)512*4608;                             // 6400x4608 bf16

  // ---- fc1 (bf16 MFMA) : HBF aliases QKV region
  unsigned short* HBF = (unsigned short*)QKV;
  k_cvt<<<(25600*1024/4 + 255)/256, 256, 0, stream>>>(hin, HBF, 25600*1024/4);
  k_wt<<<dim3(1024/64, 512/64), 256, 0, stream>>>(fc1w, WT, 1024, 512);
  k_gemm_bf<<<dim3(512/128, 25600/128), 256, 0, stream>>>(HBF, WT, fc1b, X + DMODEL, 25600, 512, 1024, 1);
  k_setcls<<<1, 512, 0, stream>>>(cls, X);

  run_attention(L1, X, XN, QKV, QL, KL, A2, Z, Z2, XZ, U, W, AV, W2, HM, AVP, SUMP, ABF, WT, stream);

  // ---- PPEG
  k_dw2<<<dim3(100, 32), 256, 0, stream>>>(X, in[iw7], in[ib7], in[iw5], in[ib5], DWOUT);
  k_wbt<<<512, 256, 0, stream>>>(in[iw3], WBT);
  for (int ch = 0; ch < 4; ch++){
    int p0 = ch * 6400;
    k_im2col_bf<<<dim3(6400, 9), 256, 0, stream>>>(X, XCL, p0);
    k_gemm_bf<<<dim3(512/128, 6400/128), 256, 0, stream>>>(XCL, WBT, in[ib3], DWOUT + (size_t)p0*DMODEL,
                                                           6400, 512, 4608, 2);
  }
  k_copyX<<<2048, 256, 0, stream>>>(DWOUT, X);

  run_attention(L2, X, XN, QKV, QL, KL, A2, Z, Z2, XZ, U, W, AV, W2, HM, AVP, SUMP, ABF, WT, stream);

  k_final<<<1, 256, 0, stream>>>(X, in[ing], in[inb], in[ifc2w], in[ifc2b], (float*)d_out);
  k_ones<<<(51200 + 255)/256, 256, 0, stream>>>((float*)d_out, 51200);
}